// Round 10
// baseline (220.893 us; speedup 1.0000x reference)
//
#include <hip/hip_runtime.h>

#define NN 8192
#define FF 256
#define MM 128
#define HSLOTS 262144   // power of 2, 2x edge count

typedef __attribute__((ext_vector_type(8))) short bf16x8;
typedef __attribute__((ext_vector_type(4))) float f32x4;

// ws layout (bytes):
// [0, 16K): partial sums, 3 arrays x 64 slots, 64B apart; + done-counter
// [16K, +2MB): zb bf16 [NN][MM]  (row-major, for edge path)
// [.., +1MB): dedup hash set (u32 keys, 0 = empty; zeroed in prep_w)
// [.., +64KB): WmuT bf16 [MM][FF]
// [.., +64KB): WsgT bf16 [MM][FF]
// [.., +2MB): zf bf16 fragment-interleaved: unit[(rt*16+kq)*16+l15] = 8 shorts
#define P_KL    0
#define P_EDGE  (64 * 16)
#define P_SP    (128 * 16)
#define CNT_IDX 3072
#define Z_OFF   16384
#define Z_BYTES (NN * MM * 2)
#define HASH_OFF (Z_OFF + Z_BYTES)
#define WT_OFF  (HASH_OFF + HSLOTS * 4)
#define WT_BYTES (MM * FF * 2)
#define ZF_OFF  (WT_OFF + 2 * WT_BYTES)

#define TBLOCKS 1056   // tile-pair blocks covering 2080 upper-tri tiles

__device__ __forceinline__ float wave_reduce(float v) {
    #pragma unroll
    for (int off = 32; off > 0; off >>= 1) v += __shfl_down(v, off);
    return v;
}
__device__ __forceinline__ unsigned short f2bf(float f) {
    unsigned int u = __float_as_uint(f);
    u += 0x7fffu + ((u >> 16) & 1u);   // round to nearest even
    return (unsigned short)(u >> 16);
}
__device__ __forceinline__ int4 pack8(float4 a, float4 b) {
    int4 p;
    p.x = (int)f2bf(a.x) | ((int)f2bf(a.y) << 16);
    p.y = (int)f2bf(a.z) | ((int)f2bf(a.w) << 16);
    p.z = (int)f2bf(b.x) | ((int)f2bf(b.y) << 16);
    p.w = (int)f2bf(b.z) | ((int)f2bf(b.w) << 16);
    return p;
}

// ---- prep: W transpose->bf16, zero partials(+counter), zero hash table ---
__global__ __launch_bounds__(256)
void prep_w(const float* __restrict__ Wmu, const float* __restrict__ Wsg,
            unsigned short* __restrict__ WmuT, unsigned short* __restrict__ WsgT,
            float* __restrict__ part, unsigned int* __restrict__ ht) {
    const int t = blockIdx.x * 256 + threadIdx.x;   // 0..32767
    const int n = t >> 8, f = t & 255;
    WmuT[t] = f2bf(Wmu[f * MM + n]);
    WsgT[t] = f2bf(Wsg[f * MM + n]);
    if (t < 4096) part[t] = 0.f;          // 16 KB: slots + done-counter
    uint4 z4 = {0u, 0u, 0u, 0u};
    ((uint4*)ht)[t * 2]     = z4;
    ((uint4*)ht)[t * 2 + 1] = z4;
}

// ---- encoder: MFMA GEMMs, dual-writes zb (row-major) + zf (fragment) -----
#define XP_I4 33   // int4 pitch per x row (32 data + 1 pad)
#define XP_S  264

__global__ __launch_bounds__(256)
void encoder_mfma(const float* __restrict__ x, const float* __restrict__ eps,
                  const unsigned short* __restrict__ WmuT,
                  const unsigned short* __restrict__ WsgT,
                  const float* __restrict__ bmu, const float* __restrict__ bsg,
                  unsigned short* __restrict__ zb, unsigned short* __restrict__ zf,
                  float* __restrict__ part) {
    __shared__ int4 ax[16 * XP_I4];   // 8.4 KB: 16 x-rows, K=256 bf16
    __shared__ float red[4];
    const int tid = threadIdx.x;
    const int wid = tid >> 6, lane = tid & 63;
    const int l15 = lane & 15, quad = lane >> 4;
    const int row0 = blockIdx.x * 16;

    {   // stage 16 rows x 256 cols of x as bf16
        const int r = tid >> 4, ch = tid & 15;
        const float4* g0 = (const float4*)(x + (size_t)(row0 + r) * FF + ch * 8);
        const float4* g1 = (const float4*)(x + (size_t)(row0 + r) * FF + (ch + 16) * 8);
        ax[r * XP_I4 + ch]      = pack8(g0[0], g0[1]);
        ax[r * XP_I4 + ch + 16] = pack8(g1[0], g1[1]);
    }
    __syncthreads();

    const short* sax = (const short*)ax;
    const int4* wtm = (const int4*)WmuT;   // row n = 32 int4 (K=256)
    const int4* wts = (const int4*)WsgT;

    f32x4 zero4 = {0.f, 0.f, 0.f, 0.f};
    f32x4 accm[2], accl[2];
    accm[0] = accm[1] = accl[0] = accl[1] = zero4;

    #pragma unroll
    for (int ks = 0; ks < 8; ++ks) {       // K = 8 x 32
        const bf16x8 a = *(const bf16x8*)&sax[l15 * XP_S + ks * 32 + quad * 8];
        #pragma unroll
        for (int j = 0; j < 2; ++j) {
            const int n = wid * 32 + j * 16 + l15;
            const bf16x8 bmf = *(const bf16x8*)&wtm[n * 32 + ks * 4 + quad];
            const bf16x8 bsf = *(const bf16x8*)&wts[n * 32 + ks * 4 + quad];
            accm[j] = __builtin_amdgcn_mfma_f32_16x16x32_bf16(a, bmf, accm[j], 0, 0, 0);
            accl[j] = __builtin_amdgcn_mfma_f32_16x16x32_bf16(a, bsf, accl[j], 0, 0, 0);
        }
    }

    // epilogue: C map col=lane&15, row=quad*4+reg [m89]
    const int rt = row0 >> 4;
    float klp = 0.f;
    #pragma unroll
    for (int j = 0; j < 2; ++j) {
        const int col = wid * 32 + j * 16 + l15;
        const float bm = bmu[col], bs = bsg[col];
        const int kq = col >> 3, c7 = col & 7;
        #pragma unroll
        for (int r = 0; r < 4; ++r) {
            const int row = row0 + quad * 4 + r;
            const float mu = accm[j][r] + bm;
            const float ls = accl[j][r] + bs;
            const float sg = __expf(ls);
            const float zz = fmaf(sg, eps[(size_t)row * MM + col], mu);
            const unsigned short zv = f2bf(zz);
            zb[(size_t)row * MM + col] = zv;
            zf[(size_t)(((rt * 16 + kq) * 16) + quad * 4 + r) * 8 + c7] = zv;
            klp += 0.5f * (sg * sg + mu * mu - 1.f) - ls;
        }
    }

    klp = wave_reduce(klp);
    if (lane == 0) red[wid] = klp;
    __syncthreads();
    if (tid == 0)
        atomicAdd(&part[P_KL + (blockIdx.x & 63) * 16],
                  red[0] + red[1] + red[2] + red[3]);
}

// ---- helpers --------------------------------------------------------------
__device__ __forceinline__ float dotpair(unsigned int a, unsigned int b) {
    const float al = __uint_as_float(a << 16);
    const float ah = __uint_as_float(a & 0xffff0000u);
    const float bl = __uint_as_float(b << 16);
    const float bh = __uint_as_float(b & 0xffff0000u);
    return fmaf(al, bl, ah * bh);
}

// ---- fused: tile-pair blocks + edge blocks + last-block combine ----------
__global__ __launch_bounds__(256)
void fused_kernel(const int* __restrict__ ei, int E,
                  const unsigned short* __restrict__ zb,
                  const unsigned short* __restrict__ zf,
                  unsigned int* __restrict__ ht, float* __restrict__ part,
                  float* __restrict__ out) {
    const int tid = threadIdx.x;
    const int wid = tid >> 6, lane = tid & 63;
    const int l15 = lane & 15, quad = lane >> 4;

    if ((int)blockIdx.x < TBLOCKS) {
        // ============ tile path: 1-2 upper-tri 128x128 tiles =============
        int q = blockIdx.x;
        int bi = 0, P = 32;                 // row bi has (65-bi)>>1 pairs
        while (q >= P) { q -= P; ++bi; P = (65 - bi) >> 1; }
        const int bj0 = bi + 2 * q;
        const int ntile = (bj0 < 63) ? 2 : 1;

        const int wm = wid >> 1, wn = wid & 1;
        const bf16x8* zv = (const bf16x8*)zf;   // 16-B units
        const int art = bi * 8 + wm * 4;        // A row-tiles art..art+3

        float tsum = 0.f;
        for (int t = 0; t < ntile; ++t) {
            const int bj = bj0 + t;
            const int brt = bj * 8 + wn * 4;

            f32x4 zero4 = {0.f, 0.f, 0.f, 0.f};
            f32x4 acc[4][4];
            #pragma unroll
            for (int i = 0; i < 4; ++i)
                #pragma unroll
                for (int j = 0; j < 4; ++j) acc[i][j] = zero4;

            bf16x8 aA[4], bA[4], aB[4], bB[4];
            #define LOADF(dstA, dstB, ks)                                         \
                _Pragma("unroll")                                                 \
                for (int u = 0; u < 4; ++u) {                                     \
                    dstA[u] = zv[((art + u) * 16 + (ks) * 4 + quad) * 16 + l15];  \
                    dstB[u] = zv[((brt + u) * 16 + (ks) * 4 + quad) * 16 + l15];  \
                }
            #define MFMAS(srcA, srcB)                                             \
                _Pragma("unroll")                                                 \
                for (int i = 0; i < 4; ++i)                                       \
                    _Pragma("unroll")                                             \
                    for (int j = 0; j < 4; ++j)                                   \
                        acc[i][j] = __builtin_amdgcn_mfma_f32_16x16x32_bf16(      \
                            srcA[i], srcB[j], acc[i][j], 0, 0, 0);

            LOADF(aA, bA, 0)
            LOADF(aB, bB, 1)
            MFMAS(aA, bA)
            LOADF(aA, bA, 2)
            MFMAS(aB, bB)
            LOADF(aB, bB, 3)
            MFMAS(aA, bA)
            MFMAS(aB, bB)
            #undef LOADF
            #undef MFMAS

            // softplus(v) ~= max(v,0) + e - e^2/2, e=exp(-|v|); err<=e^3/3
            if (bi != bj) {
                #pragma unroll
                for (int i = 0; i < 4; ++i)
                    #pragma unroll
                    for (int j = 0; j < 4; ++j)
                        #pragma unroll
                        for (int r = 0; r < 4; ++r) {
                            const float v = acc[i][j][r];
                            const float e = __expf(-fabsf(v));
                            tsum += fmaxf(v, 0.f) + e * fmaf(e, -0.5f, 1.f);
                        }
            } else {
                const int rbase = wm * 64 + quad * 4;
                const int cbase = wn * 64 + l15;
                #pragma unroll
                for (int i = 0; i < 4; ++i)
                    #pragma unroll
                    for (int j = 0; j < 4; ++j)
                        #pragma unroll
                        for (int r = 0; r < 4; ++r)
                            if (cbase + j * 16 > rbase + i * 16 + r) {
                                const float v = acc[i][j][r];
                                const float e = __expf(-fabsf(v));
                                tsum += fmaxf(v, 0.f) + e * fmaf(e, -0.5f, 1.f);
                            }
            }
        }

        tsum = wave_reduce(tsum);
        if (lane == 0)
            atomicAdd(&part[P_SP + ((blockIdx.x * 4 + wid) & 63) * 16], tsum);
    } else {
        // ============ edge path: 256 edges/block, 1 per lane =============
        const int eb = blockIdx.x - TBLOCKS;
        const int e = eb * 256 + tid;
        int i = 0, j = 0;
        if (e < E) { i = ei[e]; j = ei[E + e]; }
        const int a = min(i, j), b = max(i, j);
        bool first = false;
        if (e < E && i != j) {
            const unsigned int key = (unsigned int)a * NN + b;  // >=1, <2^26
            unsigned int slot = (key * 2654435761u) & (HSLOTS - 1);
            for (;;) {   // all 256 CASes of the block fly in parallel
                const unsigned int old = atomicCAS(&ht[slot], 0u, key);
                if (old == 0u) { first = true; break; }
                if (old == key) break;
                slot = (slot + 1) & (HSLOTS - 1);
            }
        }
        // ballot-queue: each 16-lane group walks its winners
        const int g = lane >> 4;
        const unsigned long long m = __ballot(first);
        unsigned int gm = (unsigned int)((m >> (g * 16)) & 0xffffULL);
        float gacc = 0.f;
        while (gm) {
            const int w = __ffs(gm) - 1;
            gm &= gm - 1;
            const int src = (g << 4) | w;
            const int aw = __shfl(a, src);
            const int bw = __shfl(b, src);
            const uint4 ua = ((const uint4*)(zb + (size_t)aw * MM))[l15];
            const uint4 ub = ((const uint4*)(zb + (size_t)bw * MM))[l15];
            float s = dotpair(ua.x, ub.x) + dotpair(ua.y, ub.y)
                    + dotpair(ua.z, ub.z) + dotpair(ua.w, ub.w);
            s += __shfl_down(s, 8);
            s += __shfl_down(s, 4);
            s += __shfl_down(s, 2);
            s += __shfl_down(s, 1);
            if (l15 == 0) gacc += s;
        }
        gacc = wave_reduce(gacc);
        if (lane == 0)
            atomicAdd(&part[P_EDGE + ((eb * 4 + wid) & 63) * 16], gacc);
    }

    // ============ last-block combine ============
    __shared__ unsigned int lastflag;
    __threadfence();   // make this block's part-atomics visible first
    if (tid == 0) {
        const unsigned int done =
            atomicAdd((unsigned int*)&part[CNT_IDX], 1u);
        lastflag = (done == gridDim.x - 1) ? 1u : 0u;
    }
    __syncthreads();
    if (lastflag && tid < 64) {
        __threadfence();
        float v = __hip_atomic_load(&part[P_SP + tid * 16],
                                    __ATOMIC_RELAXED, __HIP_MEMORY_SCOPE_AGENT)
                - __hip_atomic_load(&part[P_EDGE + tid * 16],
                                    __ATOMIC_RELAXED, __HIP_MEMORY_SCOPE_AGENT)
                + 0.001f * __hip_atomic_load(&part[P_KL + tid * 16],
                                    __ATOMIC_RELAXED, __HIP_MEMORY_SCOPE_AGENT);
        v = wave_reduce(v);
        if (tid == 0) out[0] = v;
    }
}

extern "C" void kernel_launch(void* const* d_in, const int* in_sizes, int n_in,
                              void* d_out, int out_size, void* d_ws, size_t ws_size,
                              hipStream_t stream) {
    const float* x   = (const float*)d_in[0];
    const int* ei    = (const int*)d_in[1];     // int32 on device
    const float* eps = (const float*)d_in[2];
    const float* Wmu = (const float*)d_in[3];
    const float* bmu = (const float*)d_in[4];
    const float* Wsg = (const float*)d_in[5];
    const float* bsg = (const float*)d_in[6];
    float* out = (float*)d_out;
    char* ws = (char*)d_ws;

    float* part = (float*)ws;
    unsigned short* zb = (unsigned short*)(ws + Z_OFF);
    unsigned int* ht = (unsigned int*)(ws + HASH_OFF);
    unsigned short* WmuT = (unsigned short*)(ws + WT_OFF);
    unsigned short* WsgT = (unsigned short*)(ws + WT_OFF + WT_BYTES);
    unsigned short* zf = (unsigned short*)(ws + ZF_OFF);
    const int E = in_sizes[1] / 2;
    const int eblocks = (E + 255) / 256;

    prep_w<<<128, 256, 0, stream>>>(Wmu, Wsg, WmuT, WsgT, part, ht);
    encoder_mfma<<<NN / 16, 256, 0, stream>>>(x, eps, WmuT, WsgT, bmu, bsg,
                                              zb, zf, part);
    fused_kernel<<<TBLOCKS + eblocks, 256, 0, stream>>>(ei, E, zb, zf, ht,
                                                        part, out);
}